// Round 1
// baseline (805.431 us; speedup 1.0000x reference)
//
#include <hip/hip_runtime.h>

#define N_NODES 100000
#define N_EDGES 600000
#define H 128

// ---------------------------------------------------------------------------
// Phase 1: edge scatter. One 64-lane wave per edge: lanes read the sender's
// 128-float row as float2 (512B coalesced) and atomically add into the
// receiver's agg row. Lane 0 bumps the degree counter.
// ---------------------------------------------------------------------------
__global__ __launch_bounds__(256) void scatter_kernel(
    const float* __restrict__ x,
    const int* __restrict__ senders,
    const int* __restrict__ receivers,
    float* __restrict__ agg,
    float* __restrict__ deg)
{
    int e = blockIdx.x * 4 + (threadIdx.x >> 6);
    if (e >= N_EDGES) return;
    int lane = threadIdx.x & 63;
    int s = senders[e];
    int r = receivers[e];
    const float2* xrow = (const float2*)(x + (size_t)s * H);
    float2 v = xrow[lane];
    float* ar = agg + (size_t)r * H + lane * 2;
    unsafeAtomicAdd(ar, v.x);
    unsafeAtomicAdd(ar + 1, v.y);
    if (lane == 0) unsafeAtomicAdd(deg + r, 1.0f);
}

// ---------------------------------------------------------------------------
// Phase 2: fused dual-GEMM + bias + ReLU.
// out[n,:] = relu( x[n,:] @ Ws  +  (agg[n,:]/max(deg[n],1)) @ Wm  +  b )
// Block tile: 32 nodes x 128 cols, K tiled by 32. Weights + activations
// staged in LDS (40 KB). Each thread: 4 nodes x 4 cols in registers.
// ---------------------------------------------------------------------------
__global__ __launch_bounds__(256) void gemm_kernel(
    const float* __restrict__ x,
    const float* __restrict__ agg,
    const float* __restrict__ deg,
    const float* __restrict__ Ws,
    const float* __restrict__ Wm,
    const float* __restrict__ bias,
    float* __restrict__ out)
{
    __shared__ float ws_t[32][H];   // 16 KB
    __shared__ float wm_t[32][H];   // 16 KB
    __shared__ float xs[32][32];    // 4 KB
    __shared__ float ms[32][32];    // 4 KB

    const int t  = threadIdx.x;
    const int g  = t >> 5;          // node group 0..7
    const int c4 = (t & 31) << 2;   // column * 4
    const int n0 = blockIdx.x * 32; // 100000 = 3125 * 32 exactly, no tail

    float4 b4 = *(const float4*)(bias + c4);
    float4 acc[4];
#pragma unroll
    for (int i = 0; i < 4; ++i) acc[i] = b4;

    // staging coordinates: thread t loads row (t>>3), 4 cols at (t&7)*4
    const int snl = t >> 3;
    const int skq = (t & 7) << 2;
    const float dsv = deg[n0 + snl];
    const float inv = 1.0f / fmaxf(dsv, 1.0f);

    for (int k0 = 0; k0 < H; k0 += 32) {
        __syncthreads();  // protect previous tile from overwrite
        // stage weight tiles: rows k0..k0+31, all 128 cols (contiguous 16 KB)
        {
            const float4* wsg = (const float4*)(Ws + k0 * H);
            const float4* wmg = (const float4*)(Wm + k0 * H);
            float4* wsl = (float4*)&ws_t[0][0];
            float4* wml = (float4*)&wm_t[0][0];
#pragma unroll
            for (int i = 0; i < 4; ++i) {
                wsl[t + i * 256] = wsg[t + i * 256];
                wml[t + i * 256] = wmg[t + i * 256];
            }
        }
        // stage x tile and (agg/deg) tile
        {
            float4 xv = *(const float4*)(x + (size_t)(n0 + snl) * H + k0 + skq);
            *(float4*)&xs[snl][skq] = xv;
            float4 av = *(const float4*)(agg + (size_t)(n0 + snl) * H + k0 + skq);
            av.x *= inv; av.y *= inv; av.z *= inv; av.w *= inv;
            *(float4*)&ms[snl][skq] = av;
        }
        __syncthreads();

        for (int kk = 0; kk < 32; kk += 4) {
            float xv[4][4], mv[4][4];
#pragma unroll
            for (int i = 0; i < 4; ++i) {
                int nl = g * 4 + i;
                float4 a = *(const float4*)&xs[nl][kk];
                xv[i][0] = a.x; xv[i][1] = a.y; xv[i][2] = a.z; xv[i][3] = a.w;
                float4 m = *(const float4*)&ms[nl][kk];
                mv[i][0] = m.x; mv[i][1] = m.y; mv[i][2] = m.z; mv[i][3] = m.w;
            }
#pragma unroll
            for (int j = 0; j < 4; ++j) {
                float4 w0 = *(const float4*)&ws_t[kk + j][c4];
                float4 w1 = *(const float4*)&wm_t[kk + j][c4];
#pragma unroll
                for (int i = 0; i < 4; ++i) {
                    acc[i].x += xv[i][j] * w0.x + mv[i][j] * w1.x;
                    acc[i].y += xv[i][j] * w0.y + mv[i][j] * w1.y;
                    acc[i].z += xv[i][j] * w0.z + mv[i][j] * w1.z;
                    acc[i].w += xv[i][j] * w0.w + mv[i][j] * w1.w;
                }
            }
        }
    }

#pragma unroll
    for (int i = 0; i < 4; ++i) {
        int n = n0 + g * 4 + i;
        float4 r;
        r.x = fmaxf(acc[i].x, 0.f);
        r.y = fmaxf(acc[i].y, 0.f);
        r.z = fmaxf(acc[i].z, 0.f);
        r.w = fmaxf(acc[i].w, 0.f);
        *(float4*)(out + (size_t)n * H + c4) = r;
    }
}

extern "C" void kernel_launch(void* const* d_in, const int* in_sizes, int n_in,
                              void* d_out, int out_size, void* d_ws, size_t ws_size,
                              hipStream_t stream) {
    const float* x        = (const float*)d_in[0];
    const int*   senders  = (const int*)d_in[1];
    const int*   receivers= (const int*)d_in[2];
    const float* Ws       = (const float*)d_in[3];
    const float* Wm       = (const float*)d_in[4];
    const float* bias     = (const float*)d_in[5];
    float*       out      = (float*)d_out;

    float* agg = (float*)d_ws;                      // N_NODES * H floats (51.2 MB)
    float* deg = agg + (size_t)N_NODES * H;         // N_NODES floats (0.4 MB)

    size_t zero_bytes = (size_t)N_NODES * H * sizeof(float)
                      + (size_t)N_NODES * sizeof(float);
    hipMemsetAsync(d_ws, 0, zero_bytes, stream);

    scatter_kernel<<<(N_EDGES + 3) / 4, 256, 0, stream>>>(x, senders, receivers, agg, deg);
    gemm_kernel<<<N_NODES / 32, 256, 0, stream>>>(x, agg, deg, Ws, Wm, bias, out);
}

// Round 2
// 400.500 us; speedup vs baseline: 2.0111x; 2.0111x over previous
//
#include <hip/hip_runtime.h>

#define N_NODES 100000
#define N_EDGES 600000
#define H 128

#define SCAN_TILE 1024   // elements per scan block (256 thr x 4)
#define NB_SCAN ((N_NODES + SCAN_TILE - 1) / SCAN_TILE)  // 98

// ---------------------------------------------------------------------------
// CSR build phase A: receiver-degree histogram (int atomics)
// ---------------------------------------------------------------------------
__global__ __launch_bounds__(256) void hist_kernel(
    const int* __restrict__ receivers, int* __restrict__ degree)
{
    int e = blockIdx.x * 256 + threadIdx.x;
    if (e < N_EDGES) atomicAdd(&degree[receivers[e]], 1);
}

// ---------------------------------------------------------------------------
// CSR build phase B1: per-block exclusive scan (1024 elems/block)
// ---------------------------------------------------------------------------
__global__ __launch_bounds__(256) void scan1_kernel(
    const int* __restrict__ degree, int* __restrict__ offs, int* __restrict__ bsums)
{
    __shared__ int tsum[256];
    const int t = threadIdx.x;
    const int base = blockIdx.x * SCAN_TILE + t * 4;
    int v[4], e[4];
    int s = 0;
#pragma unroll
    for (int i = 0; i < 4; ++i) {
        v[i] = (base + i < N_NODES) ? degree[base + i] : 0;
        e[i] = s;
        s += v[i];
    }
    tsum[t] = s;
    __syncthreads();
    // Hillis-Steele inclusive scan over 256 thread sums
    for (int off = 1; off < 256; off <<= 1) {
        int val = (t >= off) ? tsum[t - off] : 0;
        __syncthreads();
        tsum[t] += val;
        __syncthreads();
    }
    int toff = tsum[t] - s;  // exclusive offset of this thread
#pragma unroll
    for (int i = 0; i < 4; ++i)
        if (base + i < N_NODES) offs[base + i] = toff + e[i];
    if (t == 255) bsums[blockIdx.x] = tsum[255];
}

// ---------------------------------------------------------------------------
// CSR build phase B2: scan the 98 block sums (single thread — trivial size)
// ---------------------------------------------------------------------------
__global__ void scan2_kernel(int* __restrict__ bsums)
{
    if (threadIdx.x == 0 && blockIdx.x == 0) {
        int run = 0;
        for (int i = 0; i < NB_SCAN; ++i) {
            int v = bsums[i];
            bsums[i] = run;
            run += v;
        }
    }
}

// ---------------------------------------------------------------------------
// CSR build phase B3: add block offsets; also init per-node fill cursors
// ---------------------------------------------------------------------------
__global__ __launch_bounds__(256) void scan3_kernel(
    int* __restrict__ offs, const int* __restrict__ bsums, int* __restrict__ cursor)
{
    int i = blockIdx.x * 256 + threadIdx.x;
    if (i < N_NODES) {
        int o = offs[i] + bsums[i >> 10];
        offs[i] = o;
        cursor[i] = o;
    }
}

// ---------------------------------------------------------------------------
// CSR build phase C: bucket senders by receiver
// ---------------------------------------------------------------------------
__global__ __launch_bounds__(256) void fill_kernel(
    const int* __restrict__ senders, const int* __restrict__ receivers,
    int* __restrict__ cursor, int* __restrict__ edge_src)
{
    int e = blockIdx.x * 256 + threadIdx.x;
    if (e < N_EDGES) {
        int r = receivers[e];
        int pos = atomicAdd(&cursor[r], 1);
        edge_src[pos] = senders[e];
    }
}

// ---------------------------------------------------------------------------
// Gather: one 64-lane wave per node. Lanes hold float2 of the 128-col row.
// Sum incoming sender rows (512B coalesced reads, L3-resident x), normalize
// by 1/max(deg,1), write agg once. No fp32 atomics.
// ---------------------------------------------------------------------------
__global__ __launch_bounds__(256) void gather_kernel(
    const float* __restrict__ x,
    const int* __restrict__ offs,
    const int* __restrict__ degree,
    const int* __restrict__ edge_src,
    float* __restrict__ agg)
{
    int node = blockIdx.x * 4 + (threadIdx.x >> 6);
    if (node >= N_NODES) return;
    int lane = threadIdx.x & 63;

    int beg = offs[node];
    int d = degree[node];
    int end = beg + d;

    float2 a0 = {0.f, 0.f}, a1 = {0.f, 0.f};
    int e = beg;
    for (; e + 1 < end; e += 2) {
        int s0 = edge_src[e];
        int s1 = edge_src[e + 1];
        float2 v0 = *(const float2*)(x + (size_t)s0 * H + lane * 2);
        float2 v1 = *(const float2*)(x + (size_t)s1 * H + lane * 2);
        a0.x += v0.x; a0.y += v0.y;
        a1.x += v1.x; a1.y += v1.y;
    }
    if (e < end) {
        int s0 = edge_src[e];
        float2 v0 = *(const float2*)(x + (size_t)s0 * H + lane * 2);
        a0.x += v0.x; a0.y += v0.y;
    }
    float inv = 1.0f / fmaxf((float)d, 1.0f);
    float2 r;
    r.x = (a0.x + a1.x) * inv;
    r.y = (a0.y + a1.y) * inv;
    *(float2*)(agg + (size_t)node * H + lane * 2) = r;
}

// ---------------------------------------------------------------------------
// Fused dual-GEMM + bias + ReLU (unchanged from R1 except agg is
// pre-normalized, so the deg multiply is gone).
// out[n,:] = relu( x[n,:] @ Ws + agg[n,:] @ Wm + b )
// ---------------------------------------------------------------------------
__global__ __launch_bounds__(256) void gemm_kernel(
    const float* __restrict__ x,
    const float* __restrict__ agg,
    const float* __restrict__ Ws,
    const float* __restrict__ Wm,
    const float* __restrict__ bias,
    float* __restrict__ out)
{
    __shared__ float ws_t[32][H];   // 16 KB
    __shared__ float wm_t[32][H];   // 16 KB
    __shared__ float xs[32][32];    // 4 KB
    __shared__ float ms[32][32];    // 4 KB

    const int t  = threadIdx.x;
    const int g  = t >> 5;          // node group 0..7
    const int c4 = (t & 31) << 2;   // column * 4
    const int n0 = blockIdx.x * 32; // 100000 = 3125 * 32 exactly, no tail

    float4 b4 = *(const float4*)(bias + c4);
    float4 acc[4];
#pragma unroll
    for (int i = 0; i < 4; ++i) acc[i] = b4;

    const int snl = t >> 3;
    const int skq = (t & 7) << 2;

    for (int k0 = 0; k0 < H; k0 += 32) {
        __syncthreads();
        {
            const float4* wsg = (const float4*)(Ws + k0 * H);
            const float4* wmg = (const float4*)(Wm + k0 * H);
            float4* wsl = (float4*)&ws_t[0][0];
            float4* wml = (float4*)&wm_t[0][0];
#pragma unroll
            for (int i = 0; i < 4; ++i) {
                wsl[t + i * 256] = wsg[t + i * 256];
                wml[t + i * 256] = wmg[t + i * 256];
            }
        }
        {
            float4 xv = *(const float4*)(x + (size_t)(n0 + snl) * H + k0 + skq);
            *(float4*)&xs[snl][skq] = xv;
            float4 av = *(const float4*)(agg + (size_t)(n0 + snl) * H + k0 + skq);
            *(float4*)&ms[snl][skq] = av;
        }
        __syncthreads();

        for (int kk = 0; kk < 32; kk += 4) {
            float xv[4][4], mv[4][4];
#pragma unroll
            for (int i = 0; i < 4; ++i) {
                int nl = g * 4 + i;
                float4 a = *(const float4*)&xs[nl][kk];
                xv[i][0] = a.x; xv[i][1] = a.y; xv[i][2] = a.z; xv[i][3] = a.w;
                float4 m = *(const float4*)&ms[nl][kk];
                mv[i][0] = m.x; mv[i][1] = m.y; mv[i][2] = m.z; mv[i][3] = m.w;
            }
#pragma unroll
            for (int j = 0; j < 4; ++j) {
                float4 w0 = *(const float4*)&ws_t[kk + j][c4];
                float4 w1 = *(const float4*)&wm_t[kk + j][c4];
#pragma unroll
                for (int i = 0; i < 4; ++i) {
                    acc[i].x += xv[i][j] * w0.x + mv[i][j] * w1.x;
                    acc[i].y += xv[i][j] * w0.y + mv[i][j] * w1.y;
                    acc[i].z += xv[i][j] * w0.z + mv[i][j] * w1.z;
                    acc[i].w += xv[i][j] * w0.w + mv[i][j] * w1.w;
                }
            }
        }
    }

#pragma unroll
    for (int i = 0; i < 4; ++i) {
        int n = n0 + g * 4 + i;
        float4 r;
        r.x = fmaxf(acc[i].x, 0.f);
        r.y = fmaxf(acc[i].y, 0.f);
        r.z = fmaxf(acc[i].z, 0.f);
        r.w = fmaxf(acc[i].w, 0.f);
        *(float4*)(out + (size_t)n * H + c4) = r;
    }
}

extern "C" void kernel_launch(void* const* d_in, const int* in_sizes, int n_in,
                              void* d_out, int out_size, void* d_ws, size_t ws_size,
                              hipStream_t stream) {
    const float* x        = (const float*)d_in[0];
    const int*   senders  = (const int*)d_in[1];
    const int*   receivers= (const int*)d_in[2];
    const float* Ws       = (const float*)d_in[3];
    const float* Wm       = (const float*)d_in[4];
    const float* bias     = (const float*)d_in[5];
    float*       out      = (float*)d_out;

    // workspace layout (all 256B-aligned)
    char* p = (char*)d_ws;
    float* agg     = (float*)p;                 p += (size_t)N_NODES * H * sizeof(float); // 51.2 MB
    int* degree    = (int*)p;                   p += (size_t)N_NODES * sizeof(int);
    int* offs      = (int*)p;                   p += (size_t)N_NODES * sizeof(int);
    int* cursor    = (int*)p;                   p += (size_t)N_NODES * sizeof(int);
    int* bsums     = (int*)p;                   p += 256 * sizeof(int);
    int* edge_src  = (int*)p;                   p += (size_t)N_EDGES * sizeof(int);

    hipMemsetAsync(degree, 0, (size_t)N_NODES * sizeof(int), stream);

    hist_kernel <<<(N_EDGES + 255) / 256, 256, 0, stream>>>(receivers, degree);
    scan1_kernel<<<NB_SCAN, 256, 0, stream>>>(degree, offs, bsums);
    scan2_kernel<<<1, 64, 0, stream>>>(bsums);
    scan3_kernel<<<(N_NODES + 255) / 256, 256, 0, stream>>>(offs, bsums, cursor);
    fill_kernel <<<(N_EDGES + 255) / 256, 256, 0, stream>>>(senders, receivers, cursor, edge_src);
    gather_kernel<<<(N_NODES + 3) / 4, 256, 0, stream>>>(x, offs, degree, edge_src, agg);
    gemm_kernel <<<N_NODES / 32, 256, 0, stream>>>(x, agg, Ws, Wm, bias, out);
}

// Round 3
// 249.734 us; speedup vs baseline: 3.2251x; 1.6037x over previous
//
#include <hip/hip_runtime.h>

#define N_NODES 100000
#define N_EDGES 600000
#define H 128

#define SCAN_TILE 1024
#define NB_SCAN ((N_NODES + SCAN_TILE - 1) / SCAN_TILE)  // 98
#define N_STRIPS (N_NODES / 16)                          // 6250

typedef short v8s __attribute__((ext_vector_type(8)));   // 8 bf16 (4 VGPRs)
typedef float v4f __attribute__((ext_vector_type(4)));   // 4 fp32 acc

__device__ __forceinline__ unsigned short f2bf(float f) {
    unsigned int u = __float_as_uint(f);
    u = (u + 0x7fffu + ((u >> 16) & 1u)) >> 16;   // round-nearest-even
    return (unsigned short)u;
}
__device__ __forceinline__ unsigned int pack2bf(float a, float b) {
    return (unsigned int)f2bf(a) | ((unsigned int)f2bf(b) << 16);
}

// ---------------------------------------------------------------------------
// Convert x (fp32, N*H) -> bf16 packed. 3.2M float4s, 12500 blocks exactly.
// ---------------------------------------------------------------------------
__global__ __launch_bounds__(256) void convert_x_kernel(
    const float* __restrict__ x, unsigned int* __restrict__ xb)
{
    int i = blockIdx.x * 256 + threadIdx.x;       // float4 index
    float4 v = ((const float4*)x)[i];
    uint2 o;
    o.x = pack2bf(v.x, v.y);
    o.y = pack2bf(v.z, v.w);
    ((uint2*)xb)[i] = o;
}

// ---------------------------------------------------------------------------
// Build Bperm: weights in MFMA B-fragment order.
// frag f = (kstep*8 + ntile)*64 + lane holds B[k=kstep*32+q*8+j][n=ntile*16+(lane&15)]
// where B = [Ws; Wm] (K=256, N=128). 4096 threads, one frag each.
// ---------------------------------------------------------------------------
__global__ __launch_bounds__(256) void prep_w_kernel(
    const float* __restrict__ Ws, const float* __restrict__ Wm,
    unsigned short* __restrict__ Bperm)
{
    int t = blockIdx.x * 256 + threadIdx.x;       // 0..4095
    int kstep = t >> 9;
    int ntile = (t >> 6) & 7;
    int lane  = t & 63;
    int q = lane >> 4;
    int n = ntile * 16 + (lane & 15);
#pragma unroll
    for (int j = 0; j < 8; ++j) {
        int k = kstep * 32 + q * 8 + j;
        float v = (k < H) ? Ws[k * H + n] : Wm[(k - H) * H + n];
        Bperm[(size_t)t * 8 + j] = f2bf(v);
    }
}

// ---------------------------------------------------------------------------
// CSR build: histogram -> 3-phase exclusive scan -> bucket fill
// ---------------------------------------------------------------------------
__global__ __launch_bounds__(256) void hist_kernel(
    const int* __restrict__ receivers, int* __restrict__ degree)
{
    int e = blockIdx.x * 256 + threadIdx.x;
    if (e < N_EDGES) atomicAdd(&degree[receivers[e]], 1);
}

__global__ __launch_bounds__(256) void scan1_kernel(
    const int* __restrict__ degree, int* __restrict__ offs, int* __restrict__ bsums)
{
    __shared__ int tsum[256];
    const int t = threadIdx.x;
    const int base = blockIdx.x * SCAN_TILE + t * 4;
    int v[4], e[4];
    int s = 0;
#pragma unroll
    for (int i = 0; i < 4; ++i) {
        v[i] = (base + i < N_NODES) ? degree[base + i] : 0;
        e[i] = s;
        s += v[i];
    }
    tsum[t] = s;
    __syncthreads();
    for (int off = 1; off < 256; off <<= 1) {
        int val = (t >= off) ? tsum[t - off] : 0;
        __syncthreads();
        tsum[t] += val;
        __syncthreads();
    }
    int toff = tsum[t] - s;
#pragma unroll
    for (int i = 0; i < 4; ++i)
        if (base + i < N_NODES) offs[base + i] = toff + e[i];
    if (t == 255) bsums[blockIdx.x] = tsum[255];
}

__global__ void scan2_kernel(int* __restrict__ bsums)
{
    if (threadIdx.x == 0 && blockIdx.x == 0) {
        int run = 0;
        for (int i = 0; i < NB_SCAN; ++i) {
            int v = bsums[i];
            bsums[i] = run;
            run += v;
        }
    }
}

__global__ __launch_bounds__(256) void scan3_kernel(
    int* __restrict__ offs, const int* __restrict__ bsums, int* __restrict__ cursor)
{
    int i = blockIdx.x * 256 + threadIdx.x;
    if (i < N_NODES) {
        int o = offs[i] + bsums[i >> 10];
        offs[i] = o;
        cursor[i] = o;
    }
}

__global__ __launch_bounds__(256) void fill_kernel(
    const int* __restrict__ senders, const int* __restrict__ receivers,
    int* __restrict__ cursor, int* __restrict__ edge_src)
{
    int e = blockIdx.x * 256 + threadIdx.x;
    if (e < N_EDGES) {
        int r = receivers[e];
        int pos = atomicAdd(&cursor[r], 1);
        edge_src[pos] = senders[e];
    }
}

// ---------------------------------------------------------------------------
// Gather (bf16 x): one wave per node, lane holds 2 cols. Sum sender rows
// (256B coalesced reads, x_bf16 L3-resident), normalize, write agg as bf16.
// ---------------------------------------------------------------------------
__global__ __launch_bounds__(256) void gather_kernel(
    const unsigned short* __restrict__ xb,
    const int* __restrict__ offs,
    const int* __restrict__ degree,
    const int* __restrict__ edge_src,
    unsigned short* __restrict__ aggb)
{
    int node = blockIdx.x * 4 + (threadIdx.x >> 6);
    if (node >= N_NODES) return;
    int lane = threadIdx.x & 63;

    int beg = offs[node];
    int d = degree[node];
    int end = beg + d;

    float a0 = 0.f, b0 = 0.f, a1 = 0.f, b1 = 0.f;
    int e = beg;
    for (; e + 1 < end; e += 2) {
        int s0 = edge_src[e];
        int s1 = edge_src[e + 1];
        unsigned int u0 = ((const unsigned int*)(xb + (size_t)s0 * H))[lane];
        unsigned int u1 = ((const unsigned int*)(xb + (size_t)s1 * H))[lane];
        a0 += __uint_as_float(u0 << 16);
        b0 += __uint_as_float(u0 & 0xffff0000u);
        a1 += __uint_as_float(u1 << 16);
        b1 += __uint_as_float(u1 & 0xffff0000u);
    }
    if (e < end) {
        int s0 = edge_src[e];
        unsigned int u0 = ((const unsigned int*)(xb + (size_t)s0 * H))[lane];
        a0 += __uint_as_float(u0 << 16);
        b0 += __uint_as_float(u0 & 0xffff0000u);
    }
    float inv = 1.0f / fmaxf((float)d, 1.0f);
    ((unsigned int*)(aggb + (size_t)node * H))[lane] =
        pack2bf((a0 + a1) * inv, (b0 + b1) * inv);
}

// ---------------------------------------------------------------------------
// MFMA GEMM: out = relu([x|agg] @ [Ws;Wm] + bias), K=256, bf16 in / fp32 acc.
// One wave per 16-node strip; 8 col-tiles x 8 k-steps = 64 mfma_f32_16x16x32.
// A-frags: 16B contiguous loads straight from xb/aggb (A[m=lane&15][k=q*8+j]).
// B-frags: Bperm, coalesced 16B/lane, L2-hot. D: col=lane&15, row=q*4+reg.
// ---------------------------------------------------------------------------
__global__ __launch_bounds__(256) void gemm_mfma_kernel(
    const unsigned short* __restrict__ xb,
    const unsigned short* __restrict__ aggb,
    const unsigned short* __restrict__ Bperm,
    const float* __restrict__ bias,
    float* __restrict__ out)
{
    int strip = blockIdx.x * 4 + (threadIdx.x >> 6);
    if (strip >= N_STRIPS) return;
    int lane = threadIdx.x & 63;
    int q  = lane >> 4;
    int mr = lane & 15;
    size_t node0 = (size_t)strip * 16;

    const unsigned short* ax = xb   + (node0 + mr) * H + q * 8;
    const unsigned short* aa = aggb + (node0 + mr) * H + q * 8;

    v4f acc[8];
#pragma unroll
    for (int nt = 0; nt < 8; ++nt) {
        float bv = bias[nt * 16 + mr];
        acc[nt] = (v4f){bv, bv, bv, bv};
    }

    const v8s* bp = (const v8s*)Bperm;
#pragma unroll
    for (int ks = 0; ks < 8; ++ks) {
        v8s afrag = (ks < 4) ? *(const v8s*)(ax + ks * 32)
                             : *(const v8s*)(aa + (ks - 4) * 32);
#pragma unroll
        for (int nt = 0; nt < 8; ++nt) {
            v8s bfrag = bp[(ks * 8 + nt) * 64 + lane];
            acc[nt] = __builtin_amdgcn_mfma_f32_16x16x32_bf16(afrag, bfrag, acc[nt], 0, 0, 0);
        }
    }

#pragma unroll
    for (int nt = 0; nt < 8; ++nt) {
#pragma unroll
        for (int r = 0; r < 4; ++r) {
            size_t row = node0 + q * 4 + r;
            out[row * H + nt * 16 + mr] = fmaxf(acc[nt][r], 0.f);
        }
    }
}

extern "C" void kernel_launch(void* const* d_in, const int* in_sizes, int n_in,
                              void* d_out, int out_size, void* d_ws, size_t ws_size,
                              hipStream_t stream) {
    const float* x        = (const float*)d_in[0];
    const int*   senders  = (const int*)d_in[1];
    const int*   receivers= (const int*)d_in[2];
    const float* Ws       = (const float*)d_in[3];
    const float* Wm       = (const float*)d_in[4];
    const float* bias     = (const float*)d_in[5];
    float*       out      = (float*)d_out;

    // workspace layout
    char* p = (char*)d_ws;
    unsigned short* xb    = (unsigned short*)p; p += (size_t)N_NODES * H * sizeof(unsigned short); // 25.6 MB
    unsigned short* aggb  = (unsigned short*)p; p += (size_t)N_NODES * H * sizeof(unsigned short); // 25.6 MB
    unsigned short* Bperm = (unsigned short*)p; p += (size_t)256 * H * sizeof(unsigned short);     // 64 KB
    int* degree   = (int*)p; p += (size_t)N_NODES * sizeof(int);
    int* offs     = (int*)p; p += (size_t)N_NODES * sizeof(int);
    int* cursor   = (int*)p; p += (size_t)N_NODES * sizeof(int);
    int* bsums    = (int*)p; p += 256 * sizeof(int);
    int* edge_src = (int*)p; p += (size_t)N_EDGES * sizeof(int);

    hipMemsetAsync(degree, 0, (size_t)N_NODES * sizeof(int), stream);

    convert_x_kernel<<<(N_NODES * H / 4) / 256, 256, 0, stream>>>(x, (unsigned int*)xb);
    prep_w_kernel  <<<16, 256, 0, stream>>>(Ws, Wm, Bperm);
    hist_kernel    <<<(N_EDGES + 255) / 256, 256, 0, stream>>>(receivers, degree);
    scan1_kernel   <<<NB_SCAN, 256, 0, stream>>>(degree, offs, bsums);
    scan2_kernel   <<<1, 64, 0, stream>>>(bsums);
    scan3_kernel   <<<(N_NODES + 255) / 256, 256, 0, stream>>>(offs, bsums, cursor);
    fill_kernel    <<<(N_EDGES + 255) / 256, 256, 0, stream>>>(senders, receivers, cursor, edge_src);
    gather_kernel  <<<(N_NODES + 3) / 4, 256, 0, stream>>>(xb, offs, degree, edge_src, aggb);
    gemm_mfma_kernel<<<(N_STRIPS + 3) / 4, 256, 0, stream>>>(xb, aggb, Bperm, bias, out);
}

// Round 4
// 237.974 us; speedup vs baseline: 3.3845x; 1.0494x over previous
//
#include <hip/hip_runtime.h>

#define N_NODES 100000
#define N_EDGES 600000
#define H 128

#define SCAN_TILE 1024
#define NB_SCAN ((N_NODES + SCAN_TILE - 1) / SCAN_TILE)  // 98

#define NB_CONV (N_NODES * H / 4 / 256)                  // 12500
#define NB_PREP 16
#define NB_HIST ((N_EDGES + 255) / 256)                  // 2344

#define GM_ROWS 64                                       // rows per wave in gemm
#define N_WUNITS ((N_NODES + GM_ROWS - 1) / GM_ROWS)     // 1563

typedef short v8s __attribute__((ext_vector_type(8)));   // 8 bf16 (4 VGPRs)
typedef float v4f __attribute__((ext_vector_type(4)));   // 4 fp32 acc

__device__ __forceinline__ unsigned short f2bf(float f) {
    unsigned int u = __float_as_uint(f);
    u = (u + 0x7fffu + ((u >> 16) & 1u)) >> 16;   // round-nearest-even
    return (unsigned short)u;
}
__device__ __forceinline__ unsigned int pack2bf(float a, float b) {
    return (unsigned int)f2bf(a) | ((unsigned int)f2bf(b) << 16);
}

// ---------------------------------------------------------------------------
// Fused prep: [0,NB_CONV) convert x->bf16 | [..+NB_PREP) permute weights |
// [..+NB_HIST) receiver-degree histogram. All three are independent.
// ---------------------------------------------------------------------------
__global__ __launch_bounds__(256) void prep_fused_kernel(
    const float* __restrict__ x, unsigned int* __restrict__ xb,
    const float* __restrict__ Ws, const float* __restrict__ Wm,
    unsigned short* __restrict__ Bperm,
    const int* __restrict__ receivers, int* __restrict__ degree)
{
    int b = blockIdx.x;
    if (b < NB_CONV) {
        int i = b * 256 + threadIdx.x;            // float4 index
        float4 v = ((const float4*)x)[i];
        uint2 o;
        o.x = pack2bf(v.x, v.y);
        o.y = pack2bf(v.z, v.w);
        ((uint2*)xb)[i] = o;
    } else if (b < NB_CONV + NB_PREP) {
        // B-fragment permute: frag f=(kstep*8+ntile)*64+lane holds
        // B[k=kstep*32+q*8+j][n=ntile*16+(lane&15)], B=[Ws;Wm] (K=256,N=128)
        int t = (b - NB_CONV) * 256 + threadIdx.x; // 0..4095
        int kstep = t >> 9;
        int ntile = (t >> 6) & 7;
        int lane  = t & 63;
        int q = lane >> 4;
        int n = ntile * 16 + (lane & 15);
#pragma unroll
        for (int j = 0; j < 8; ++j) {
            int k = kstep * 32 + q * 8 + j;
            float v = (k < H) ? Ws[k * H + n] : Wm[(k - H) * H + n];
            Bperm[(size_t)t * 8 + j] = f2bf(v);
        }
    } else {
        int e = (b - NB_CONV - NB_PREP) * 256 + threadIdx.x;
        if (e < N_EDGES) atomicAdd(&degree[receivers[e]], 1);
    }
}

// ---------------------------------------------------------------------------
// CSR scan phase 1: per-block exclusive scan (1024 elems/block)
// ---------------------------------------------------------------------------
__global__ __launch_bounds__(256) void scan1_kernel(
    const int* __restrict__ degree, int* __restrict__ offs, int* __restrict__ bsums)
{
    __shared__ int tsum[256];
    const int t = threadIdx.x;
    const int base = blockIdx.x * SCAN_TILE + t * 4;
    int v[4], e[4];
    int s = 0;
#pragma unroll
    for (int i = 0; i < 4; ++i) {
        v[i] = (base + i < N_NODES) ? degree[base + i] : 0;
        e[i] = s;
        s += v[i];
    }
    tsum[t] = s;
    __syncthreads();
    for (int off = 1; off < 256; off <<= 1) {
        int val = (t >= off) ? tsum[t - off] : 0;
        __syncthreads();
        tsum[t] += val;
        __syncthreads();
    }
    int toff = tsum[t] - s;
#pragma unroll
    for (int i = 0; i < 4; ++i)
        if (base + i < N_NODES) offs[base + i] = toff + e[i];
    if (t == 255) bsums[blockIdx.x] = tsum[255];
}

// ---------------------------------------------------------------------------
// CSR scan phase 2: parallel exclusive scan of the 98 block sums (one block)
// ---------------------------------------------------------------------------
__global__ __launch_bounds__(128) void scan2_kernel(int* __restrict__ bsums)
{
    __shared__ int s[128];
    int t = threadIdx.x;
    int v = (t < NB_SCAN) ? bsums[t] : 0;
    s[t] = v;
    __syncthreads();
    for (int off = 1; off < 128; off <<= 1) {
        int val = (t >= off) ? s[t - off] : 0;
        __syncthreads();
        s[t] += val;
        __syncthreads();
    }
    if (t < NB_SCAN) bsums[t] = s[t] - v;   // exclusive
}

// ---------------------------------------------------------------------------
// CSR scan phase 3: add block offsets; init fill cursors
// ---------------------------------------------------------------------------
__global__ __launch_bounds__(256) void scan3_kernel(
    int* __restrict__ offs, const int* __restrict__ bsums, int* __restrict__ cursor)
{
    int i = blockIdx.x * 256 + threadIdx.x;
    if (i < N_NODES) {
        int o = offs[i] + bsums[i >> 10];
        offs[i] = o;
        cursor[i] = o;
    }
}

// ---------------------------------------------------------------------------
// CSR fill: bucket senders by receiver
// ---------------------------------------------------------------------------
__global__ __launch_bounds__(256) void fill_kernel(
    const int* __restrict__ senders, const int* __restrict__ receivers,
    int* __restrict__ cursor, int* __restrict__ edge_src)
{
    int e = blockIdx.x * 256 + threadIdx.x;
    if (e < N_EDGES) {
        int r = receivers[e];
        int pos = atomicAdd(&cursor[r], 1);
        edge_src[pos] = senders[e];
    }
}

// ---------------------------------------------------------------------------
// Gather: one wave per node, lane holds 2 cols (uint = 2 bf16). 4-deep edge
// unroll for memory-level parallelism. Normalize, write agg as bf16.
// ---------------------------------------------------------------------------
__global__ __launch_bounds__(256) void gather_kernel(
    const unsigned short* __restrict__ xb,
    const int* __restrict__ offs,
    const int* __restrict__ degree,
    const int* __restrict__ edge_src,
    unsigned short* __restrict__ aggb)
{
    int node = blockIdx.x * 4 + (threadIdx.x >> 6);
    if (node >= N_NODES) return;
    int lane = threadIdx.x & 63;

    int beg = offs[node];
    int d = degree[node];
    int end = beg + d;

    float lo0 = 0.f, hi0 = 0.f, lo1 = 0.f, hi1 = 0.f;
    float lo2 = 0.f, hi2 = 0.f, lo3 = 0.f, hi3 = 0.f;
    int e = beg;
    for (; e + 3 < end; e += 4) {
        int i0 = edge_src[e];
        int i1 = edge_src[e + 1];
        int i2 = edge_src[e + 2];
        int i3 = edge_src[e + 3];
        unsigned int u0 = ((const unsigned int*)(xb + (size_t)i0 * H))[lane];
        unsigned int u1 = ((const unsigned int*)(xb + (size_t)i1 * H))[lane];
        unsigned int u2 = ((const unsigned int*)(xb + (size_t)i2 * H))[lane];
        unsigned int u3 = ((const unsigned int*)(xb + (size_t)i3 * H))[lane];
        lo0 += __uint_as_float(u0 << 16);  hi0 += __uint_as_float(u0 & 0xffff0000u);
        lo1 += __uint_as_float(u1 << 16);  hi1 += __uint_as_float(u1 & 0xffff0000u);
        lo2 += __uint_as_float(u2 << 16);  hi2 += __uint_as_float(u2 & 0xffff0000u);
        lo3 += __uint_as_float(u3 << 16);  hi3 += __uint_as_float(u3 & 0xffff0000u);
    }
    for (; e < end; ++e) {
        int i0 = edge_src[e];
        unsigned int u0 = ((const unsigned int*)(xb + (size_t)i0 * H))[lane];
        lo0 += __uint_as_float(u0 << 16);
        hi0 += __uint_as_float(u0 & 0xffff0000u);
    }
    float inv = 1.0f / fmaxf((float)d, 1.0f);
    ((unsigned int*)(aggb + (size_t)node * H))[lane] =
        pack2bf((lo0 + lo1 + lo2 + lo3) * inv, (hi0 + hi1 + hi2 + hi3) * inv);
}

// ---------------------------------------------------------------------------
// MFMA GEMM v2: out = relu([x|agg] @ [Ws;Wm] + bias), K=256, bf16/fp32-acc.
// One wave per 64 rows (4 strips of 16) — each B-frag load feeds 4 MFMAs,
// cutting B L2-traffic 4x vs one-strip waves. 256 MFMAs/wave.
// ---------------------------------------------------------------------------
__global__ __launch_bounds__(256) void gemm_mfma_kernel(
    const unsigned short* __restrict__ xb,
    const unsigned short* __restrict__ aggb,
    const unsigned short* __restrict__ Bperm,
    const float* __restrict__ bias,
    float* __restrict__ out)
{
    int wu = blockIdx.x * 4 + (threadIdx.x >> 6);
    size_t node0 = (size_t)wu * GM_ROWS;
    if (node0 >= N_NODES) return;
    int lane = threadIdx.x & 63;
    int q  = lane >> 4;
    int mr = lane & 15;

    v4f acc[4][8];
#pragma unroll
    for (int nt = 0; nt < 8; ++nt) {
        float bv = bias[nt * 16 + mr];
#pragma unroll
        for (int s = 0; s < 4; ++s) acc[s][nt] = (v4f){bv, bv, bv, bv};
    }

    const v8s* bp = (const v8s*)Bperm;
#pragma unroll
    for (int ks = 0; ks < 8; ++ks) {
        const unsigned short* base = (ks < 4) ? xb : aggb;
        int koff = (ks & 3) * 32 + q * 8;
        v8s a[4];
#pragma unroll
        for (int s = 0; s < 4; ++s) {
            size_t row = node0 + s * 16 + mr;
            if (row >= N_NODES) row = N_NODES - 1;   // tail clamp (stores guarded)
            a[s] = *(const v8s*)(base + row * H + koff);
        }
#pragma unroll
        for (int nt = 0; nt < 8; ++nt) {
            v8s bfrag = bp[(ks * 8 + nt) * 64 + lane];
#pragma unroll
            for (int s = 0; s < 4; ++s)
                acc[s][nt] = __builtin_amdgcn_mfma_f32_16x16x32_bf16(a[s], bfrag, acc[s][nt], 0, 0, 0);
        }
    }

#pragma unroll
    for (int s = 0; s < 4; ++s) {
#pragma unroll
        for (int r = 0; r < 4; ++r) {
            size_t row = node0 + s * 16 + q * 4 + r;
            if (row < N_NODES) {
#pragma unroll
                for (int nt = 0; nt < 8; ++nt)
                    out[row * H + nt * 16 + mr] = fmaxf(acc[s][nt][r], 0.f);
            }
        }
    }
}

extern "C" void kernel_launch(void* const* d_in, const int* in_sizes, int n_in,
                              void* d_out, int out_size, void* d_ws, size_t ws_size,
                              hipStream_t stream) {
    const float* x        = (const float*)d_in[0];
    const int*   senders  = (const int*)d_in[1];
    const int*   receivers= (const int*)d_in[2];
    const float* Ws       = (const float*)d_in[3];
    const float* Wm       = (const float*)d_in[4];
    const float* bias     = (const float*)d_in[5];
    float*       out      = (float*)d_out;

    // workspace layout
    char* p = (char*)d_ws;
    unsigned short* xb    = (unsigned short*)p; p += (size_t)N_NODES * H * sizeof(unsigned short); // 25.6 MB
    unsigned short* aggb  = (unsigned short*)p; p += (size_t)N_NODES * H * sizeof(unsigned short); // 25.6 MB
    unsigned short* Bperm = (unsigned short*)p; p += (size_t)256 * H * sizeof(unsigned short);     // 64 KB
    int* degree   = (int*)p; p += (size_t)N_NODES * sizeof(int);
    int* offs     = (int*)p; p += (size_t)N_NODES * sizeof(int);
    int* cursor   = (int*)p; p += (size_t)N_NODES * sizeof(int);
    int* bsums    = (int*)p; p += 256 * sizeof(int);
    int* edge_src = (int*)p; p += (size_t)N_EDGES * sizeof(int);

    hipMemsetAsync(degree, 0, (size_t)N_NODES * sizeof(int), stream);

    prep_fused_kernel<<<NB_CONV + NB_PREP + NB_HIST, 256, 0, stream>>>(
        x, (unsigned int*)xb, Ws, Wm, Bperm, receivers, degree);
    scan1_kernel<<<NB_SCAN, 256, 0, stream>>>(degree, offs, bsums);
    scan2_kernel<<<1, 128, 0, stream>>>(bsums);
    scan3_kernel<<<(N_NODES + 255) / 256, 256, 0, stream>>>(offs, bsums, cursor);
    fill_kernel <<<(N_EDGES + 255) / 256, 256, 0, stream>>>(senders, receivers, cursor, edge_src);
    gather_kernel<<<(N_NODES + 3) / 4, 256, 0, stream>>>(xb, offs, degree, edge_src, aggb);
    gemm_mfma_kernel<<<(N_WUNITS + 3) / 4, 256, 0, stream>>>(xb, aggb, Bperm, bias, out);
}